// Round 1
// baseline (161.707 us; speedup 1.0000x reference)
//
#include <hip/hip_runtime.h>

// Gaussian VQ forward, fp32 VALU implementation.
// Shapes (fixed by the problem): bs=64, dim_z=64, W=H=32 -> N=65536 rows, K=1024 codes.
//
// ws layout (32-bit words):
//   [0   .. 127 ] : 64 (kld_discrete, kld_continuous) partial-sum pairs (float)
//   [128 .. 1151] : cnorm[1024] = ||c_k||^2 (float)
//   [1152.. 2175] : counts[1024] histogram (uint)
#define WS_CNORM  128
#define WS_COUNTS 1152
#define WS_BYTES  (2176 * 4)

// Swizzled LDS word addresses. zw: 16B-granular XOR so that 16 lanes reading
// 16 different rows (r = 8*rgrp + j) at the same d hit different bank groups
// (2-way residual alias = free). qw: word-granular XOR for scalar access so
// both d-across-lanes and r-across-lanes patterns spread over all 32 banks.
__device__ __forceinline__ int zw(int r, int d) {
  return (r << 6) | (d ^ (((r >> 3) & 7) << 3));
}
__device__ __forceinline__ int qw(int r, int d) {
  return (r << 6) | (d ^ (r & 31));
}

__global__ __launch_bounds__(256) void vq_cnorm(const float* __restrict__ cb,
                                                float* __restrict__ ws) {
  int tid = blockIdx.x * 256 + threadIdx.x;  // 256 blocks -> 1024 waves
  int k = tid >> 6;
  int lane = threadIdx.x & 63;
  float v = cb[(k << 6) + lane];
  float s = v * v;
  #pragma unroll
  for (int o = 32; o > 0; o >>= 1) s += __shfl_down(s, o);
  if (lane == 0) ws[WS_CNORM + k] = s;
}

__global__ __launch_bounds__(256, 2) void vq_main(const float* __restrict__ z,
                                                  const float* __restrict__ cb,
                                                  const float* __restrict__ var_q,
                                                  float* __restrict__ ws,
                                                  float* __restrict__ out) {
  __shared__ __align__(16) float lds[16384];       // 64 KiB
  float* zl = lds;                                  // 8192 words: z tile, later zq tile
  float* cl = lds + 8192;                           // 8192 words: code chunk
  float* scr = lds + 8192;                          // reuse: 128 rows * 24 words state scratch
  int* fidx = (int*)(lds + 8192 + 3072);            // 128 words: final argmax per row
  float* redb = lds + 8192 + 3072 + 128;            // 4 words: cross-wave loss reduce

  const int t = threadIdx.x;
  const int b = blockIdx.x;                         // 512 blocks, 128 rows each
  const int bb = b >> 3;                            // batch index (8 blocks per image)
  const int p0 = (b & 7) << 7;                      // position offset within W*H
  const float w = 0.5f / fmaxf(var_q[0], 1e-10f);

  // ---- stage z tile: z[bb, d, p0+r] -> zl[r][d] (swizzled) ----
  for (int i = 0; i < 32; ++i) {
    int idx = t + i * 256;
    int d = idx >> 7, r = idx & 127;
    zl[zw(r, d)] = z[bb * 65536 + d * 1024 + p0 + r];
  }

  // per-thread online-softmax state for 8 owned rows (over this thread's code subset)
  float m[8], s1[8], s2[8], bl[8];
  int bk[8];
  #pragma unroll
  for (int j = 0; j < 8; ++j) {
    m[j] = -1e30f; s1[j] = 0.f; s2[j] = 0.f; bl[j] = -1e30f; bk[j] = 0;
  }

  const int rgrp = t & 15, cgrp = t >> 4;
  const int r0 = rgrp << 3;

  for (int ch = 0; ch < 8; ++ch) {
    __syncthreads();
    // stage 128-code chunk (contiguous 32 KiB of codebook)
    for (int i = 0; i < 32; ++i) {
      int idx = t + i * 256;
      cl[zw(idx >> 6, idx & 63)] = cb[ch * 8192 + idx];
    }
    __syncthreads();

    float acc[8][8];
    #pragma unroll
    for (int j = 0; j < 8; ++j)
      #pragma unroll
      for (int i = 0; i < 8; ++i) acc[j][i] = 0.f;

    #pragma unroll 2
    for (int d = 0; d < 64; d += 4) {
      float4 za[8], cv[8];
      #pragma unroll
      for (int j = 0; j < 8; ++j) za[j] = *(const float4*)&zl[zw(r0 + j, d)];
      #pragma unroll
      for (int i = 0; i < 8; ++i) cv[i] = *(const float4*)&cl[zw((cgrp << 3) + i, d)];
      #pragma unroll
      for (int j = 0; j < 8; ++j)
        #pragma unroll
        for (int i = 0; i < 8; ++i) {
          acc[j][i] = fmaf(za[j].x, cv[i].x, acc[j][i]);
          acc[j][i] = fmaf(za[j].y, cv[i].y, acc[j][i]);
          acc[j][i] = fmaf(za[j].z, cv[i].z, acc[j][i]);
          acc[j][i] = fmaf(za[j].w, cv[i].w, acc[j][i]);
        }
    }

    // logits (row-constant ||z||^2 dropped: l = w*(2*dot - ||c||^2)) + state update
    const int kbase = (ch << 7) + (cgrp << 3);
    float cn[8];
    #pragma unroll
    for (int i = 0; i < 8; ++i) cn[i] = ws[WS_CNORM + kbase + i];
    #pragma unroll
    for (int j = 0; j < 8; ++j) {
      float l[8];
      #pragma unroll
      for (int i = 0; i < 8; ++i) l[i] = w * (2.f * acc[j][i] - cn[i]);
      float lm = l[0];
      #pragma unroll
      for (int i = 1; i < 8; ++i) lm = fmaxf(lm, l[i]);
      float mn = fmaxf(m[j], lm);
      float sc = __expf(m[j] - mn);
      s2[j] = sc * fmaf(m[j] - mn, s1[j], s2[j]);
      s1[j] *= sc;
      #pragma unroll
      for (int i = 0; i < 8; ++i) {
        float tt = l[i] - mn;
        float e = __expf(tt);
        s1[j] += e;
        s2[j] = fmaf(tt, e, s2[j]);
        if (l[i] > bl[j]) { bl[j] = l[i]; bk[j] = kbase + i; }
      }
      m[j] = mn;
    }
  }

  // ---- butterfly-merge state across the 4 cgrp subgroups within each wave ----
  #pragma unroll
  for (int sidx = 0; sidx < 2; ++sidx) {
    const int st = 16 << sidx;
    #pragma unroll
    for (int j = 0; j < 8; ++j) {
      float om = __shfl_xor(m[j], st);
      float o1 = __shfl_xor(s1[j], st);
      float o2 = __shfl_xor(s2[j], st);
      float ob = __shfl_xor(bl[j], st);
      int ok = __shfl_xor(bk[j], st);
      float mn = fmaxf(m[j], om);
      float sa = __expf(m[j] - mn), sb = __expf(om - mn);
      s2[j] = sa * fmaf(m[j] - mn, s1[j], s2[j]) + sb * fmaf(om - mn, o1, o2);
      s1[j] = sa * s1[j] + sb * o1;
      m[j] = mn;
      if (ob > bl[j]) { bl[j] = ob; bk[j] = ok; }
    }
  }
  __syncthreads();  // all chunk reads done -> cl reusable as scratch

  const int wv = t >> 6, lane = t & 63;
  if (lane < 16) {  // lane == rgrp here
    #pragma unroll
    for (int j = 0; j < 8; ++j) {
      int r = (lane << 3) + j;
      float* p = &scr[r * 24 + wv * 6];
      p[0] = m[j]; p[1] = s1[j]; p[2] = s2[j]; p[3] = bl[j];
      ((int*)p)[4] = bk[j];
    }
  }
  __syncthreads();

  // ---- per-row final merge (one thread per row) ----
  float rowent = 0.f, d2min = 0.f;
  if (t < 128) {
    const int r = t;
    float M = -1e30f, S1 = 0.f, S2 = 0.f, BL = -1e30f;
    int BK = 0;
    #pragma unroll
    for (int s = 0; s < 4; ++s) {
      const float* p = &scr[r * 24 + s * 6];
      float om = p[0], o1 = p[1], o2 = p[2], ob = p[3];
      int ok = ((const int*)p)[4];
      float mn = fmaxf(M, om);
      float sa = __expf(M - mn), sb = __expf(om - mn);
      S2 = sa * fmaf(M - mn, S1, S2) + sb * fmaf(om - mn, o1, o2);
      S1 = sa * S1 + sb * o1;
      M = mn;
      if (ob > BL) { BL = ob; BK = ok; }
    }
    rowent = S2 / S1 - __logf(S1);  // = sum_k p*logp for this row
    // ||z_row||^2 via coalesced global re-read (L2-hot)
    float zn = 0.f;
    const float* zp = z + bb * 65536 + p0 + r;
    for (int d = 0; d < 64; ++d) { float v = zp[d * 1024]; zn = fmaf(v, v, zn); }
    d2min = zn - BL / w;  // ||z - c_best||^2
    fidx[r] = BK;
    atomicAdd((unsigned*)ws + WS_COUNTS + BK, 1u);
  }
  #pragma unroll
  for (int o = 32; o > 0; o >>= 1) {
    rowent += __shfl_down(rowent, o);
    d2min += __shfl_down(d2min, o);
  }
  if (t < 128 && lane == 0) { redb[wv * 2] = rowent; redb[wv * 2 + 1] = d2min; }
  __syncthreads();
  if (t == 0) {
    float pd = redb[0] + redb[2];
    float pc = redb[1] + redb[3];
    int slot = b & 63;  // spread atomics over 64 slot-pairs
    atomicAdd(&ws[slot * 2], pd);
    atomicAdd(&ws[slot * 2 + 1], pc);
  }
  __syncthreads();

  // ---- gather selected codes through LDS, write transposed output coalesced ----
  for (int i = 0; i < 32; ++i) {
    int idx = t + i * 256;
    int r = idx >> 6, d = idx & 63;
    zl[qw(r, d)] = cb[(fidx[r] << 6) + d];
  }
  __syncthreads();
  float* outz = out + bb * 65536 + p0;
  #pragma unroll
  for (int i = 0; i < 8; ++i) {
    int q = t + i * 256;
    int d = q >> 5, rq = q & 31;
    int r = rq << 2;
    float4 v;
    v.x = zl[qw(r + 0, d)];
    v.y = zl[qw(r + 1, d)];
    v.z = zl[qw(r + 2, d)];
    v.w = zl[qw(r + 3, d)];
    *(float4*)&outz[d * 1024 + r] = v;
  }
}

__global__ __launch_bounds__(1024) void vq_finalize(const float* __restrict__ var_q,
                                                    float* __restrict__ ws,
                                                    float* __restrict__ out) {
  __shared__ float red[48];
  int t = threadIdx.x;
  const unsigned* counts = (const unsigned*)ws + WS_COUNTS;
  float avg = (float)counts[t] * (1.0f / 65536.0f);
  float term = avg * __logf(avg + 1e-7f);
  float pd = 0.f, pc = 0.f;
  if (t < 64) { pd = ws[2 * t]; pc = ws[2 * t + 1]; }
  #pragma unroll
  for (int o = 32; o > 0; o >>= 1) {
    term += __shfl_down(term, o);
    pd += __shfl_down(pd, o);
    pc += __shfl_down(pc, o);
  }
  int wv = t >> 6, lane = t & 63;
  if (lane == 0) { red[wv * 3] = term; red[wv * 3 + 1] = pd; red[wv * 3 + 2] = pc; }
  __syncthreads();
  if (t == 0) {
    float ts = 0.f, ps = 0.f, cs = 0.f;
    #pragma unroll
    for (int i = 0; i < 16; ++i) {
      ts += red[i * 3]; ps += red[i * 3 + 1]; cs += red[i * 3 + 2];
    }
    float w = 0.5f / fmaxf(var_q[0], 1e-10f);
    out[4194304] = ps / 64.f + w * cs / 64.f;  // kld_discrete + kld_continuous
    out[4194305] = __expf(-ts);                 // perplexity
  }
}

extern "C" void kernel_launch(void* const* d_in, const int* in_sizes, int n_in,
                              void* d_out, int out_size, void* d_ws, size_t ws_size,
                              hipStream_t stream) {
  const float* z = (const float*)d_in[0];
  const float* vq = (const float*)d_in[1];
  const float* cb = (const float*)d_in[2];
  float* out = (float*)d_out;
  float* ws = (float*)d_ws;

  hipMemsetAsync(d_ws, 0, WS_BYTES, stream);
  vq_cnorm<<<256, 256, 0, stream>>>(cb, ws);
  vq_main<<<512, 256, 0, stream>>>(z, cb, vq, ws, out);
  vq_finalize<<<1, 1024, 0, stream>>>(vq, ws, out);
}

// Round 2
// 143.412 us; speedup vs baseline: 1.1276x; 1.1276x over previous
//
#include <hip/hip_runtime.h>

// Gaussian VQ forward, split-bf16 MFMA implementation.
// bs=64, dim_z=64, W=H=32 -> N=65536 rows, K=1024 codes, D=64.
//
// d2(n,k) = ||z||^2 + ||c||^2 - 2 z.c ; logit = -w*d2; drop row-const ||z||^2.
// Dot products via 3-pass split-bf16 MFMA (z_hi*c_hi + z_lo*c_hi + z_hi*c_lo),
// error ~1e-4. Argmax protected by exact fp32 rescore of the approx top-2.
//
// ws layout (bytes):
//   [0    ..  511] : 64 (kld_discrete, kld_continuous) partial pairs (float)
//   [512  .. 4607] : cnorm[1024] fp32
//   [4608 .. 8703] : counts[1024] uint
//   [8704 ..     ] : cb_hi bf16[1024][64]  (131072 B)
//   [139776 ..   ] : cb_lo bf16[1024][64]  (131072 B)
#define WS_CNORM_B  512
#define WS_COUNTS_B 4608
#define WS_CBHI_B   8704
#define WS_CBLO_B   139776
#define WS_ZERO_B   8704

typedef __attribute__((ext_vector_type(8))) short short8;
typedef __attribute__((ext_vector_type(4))) float f32x4;

__device__ __forceinline__ unsigned short f2bf(float x) {
  unsigned u = __builtin_bit_cast(unsigned, x);
  u += 0x7fffu + ((u >> 16) & 1u);
  return (unsigned short)(u >> 16);
}
__device__ __forceinline__ float bf2f(unsigned short h) {
  unsigned u = ((unsigned)h) << 16;
  return __builtin_bit_cast(float, u);
}

// epilogue gather swizzle (word-granular), same as validated round-1 kernel
__device__ __forceinline__ int qw(int r, int d) {
  return (r << 6) | (d ^ (r & 31));
}

// ---- prep: codebook -> bf16 hi/lo splits + ||c||^2 ----
__global__ __launch_bounds__(256) void vq_prep(const float* __restrict__ cb,
                                               char* __restrict__ ws) {
  int tid = blockIdx.x * 256 + threadIdx.x;   // 65536 = 1024*64
  int k = tid >> 6, d = threadIdx.x & 63;
  float v = cb[tid];
  unsigned short hi = f2bf(v);
  unsigned short lo = f2bf(v - bf2f(hi));
  ((unsigned short*)(ws + WS_CBHI_B))[tid] = hi;
  ((unsigned short*)(ws + WS_CBLO_B))[tid] = lo;
  float s = v * v;
  #pragma unroll
  for (int o = 32; o > 0; o >>= 1) s += __shfl_down(s, o);
  if (d == 0) ((float*)(ws + WS_CNORM_B))[k] = s;
}

// ---- main ----
// LDS map (bytes):
//  [0     .. 16383] z_hi bf16 [128 rows][64 k]   (XOR-swizzled, reused for out)
//  [16384 .. 32767] z_lo
//  [32768 .. 40959] c_hi bf16 [64 codes][64 k]   (per-chunk, swizzled)
//  [40960 .. 49151] c_lo
//  [49152 .. 52223] row state: 128 x {m,s1,s2,k1,k2,pad} (24 B)
//  [52224 .. 52735] fidx[128]
//  [52736 .. 52751] redb[4]
__global__ __launch_bounds__(256) void vq_main(const float* __restrict__ z,
                                               const float* __restrict__ cb,
                                               const float* __restrict__ var_q,
                                               char* __restrict__ ws,
                                               float* __restrict__ out) {
  __shared__ __align__(16) char smem[52768];

  const int t = threadIdx.x;
  const int b = blockIdx.x;          // 512 blocks: 128 rows each
  const int bb = b >> 3;
  const int p0 = (b & 7) << 7;
  const int l = t & 63, wv = t >> 6;
  const int lg = l >> 4, lr = l & 15;
  const float w = 0.5f / fmaxf(var_q[0], 1e-10f);

  // ---- stage z tile, converting fp32 -> bf16 hi/lo, swizzled [p][k] ----
  for (int i = 0; i < 32; ++i) {
    int idx = t + i * 256;
    int d = idx >> 7, p = idx & 127;
    float v = z[bb * 65536 + d * 1024 + p0 + p];
    unsigned short h = f2bf(v);
    unsigned short o = f2bf(v - bf2f(h));
    int byteoff = (p * 128 + d * 2) ^ ((p & 7) << 4);
    *(unsigned short*)(smem + byteoff) = h;
    *(unsigned short*)(smem + 16384 + byteoff) = o;
  }
  __syncthreads();

  // ---- A fragments (persistent): rows = wv*32 + rt*16 + lr, k = ks*32 + lg*8.. ----
  short8 a_hi[2][2], a_lo[2][2];
  #pragma unroll
  for (int rt = 0; rt < 2; ++rt)
    #pragma unroll
    for (int ks = 0; ks < 2; ++ks) {
      int row = wv * 32 + rt * 16 + lr;
      int byte = (row * 128 + ks * 64 + lg * 16) ^ ((row & 7) << 4);
      a_hi[rt][ks] = *(const short8*)(smem + byte);
      a_lo[rt][ks] = *(const short8*)(smem + 16384 + byte);
    }

  // per-lane online state for 8 rows (rt*4+j), over this lane's code subset
  float m[8], s1[8], s2[8], b1v[8], b2v[8];
  int b1k[8], b2k[8];
  #pragma unroll
  for (int j = 0; j < 8; ++j) {
    m[j] = -1e30f; s1[j] = 0.f; s2[j] = 0.f;
    b1v[j] = -1e30f; b2v[j] = -1e30f; b1k[j] = 0; b2k[j] = 0;
  }

  const float* cnorm = (const float*)(ws + WS_CNORM_B);

  for (int ch = 0; ch < 16; ++ch) {
    __syncthreads();
    // stage 64-code chunk (hi+lo), pre-swizzled 16B writes
    {
      const char* srcH = ws + WS_CBHI_B + ch * 8192;
      const char* srcL = ws + WS_CBLO_B + ch * 8192;
      #pragma unroll
      for (int pas = 0; pas < 2; ++pas) {
        int o = t + pas * 256;
        int dst = (o * 16) ^ (((o >> 3) & 7) << 4);
        *(f32x4*)(smem + 32768 + dst) = *(const f32x4*)(srcH + o * 16);
        *(f32x4*)(smem + 40960 + dst) = *(const f32x4*)(srcL + o * 16);
      }
    }
    __syncthreads();

    f32x4 acc[2][4] = {};
    #pragma unroll
    for (int ct = 0; ct < 4; ++ct) {
      #pragma unroll
      for (int ks = 0; ks < 2; ++ks) {
        int cr = ct * 16 + lr;
        int byte = (cr * 128 + ks * 64 + lg * 16) ^ ((cr & 7) << 4);
        short8 bhi = *(const short8*)(smem + 32768 + byte);
        short8 blo = *(const short8*)(smem + 40960 + byte);
        #pragma unroll
        for (int rt = 0; rt < 2; ++rt) {
          acc[rt][ct] = __builtin_amdgcn_mfma_f32_16x16x32_bf16(a_hi[rt][ks], bhi, acc[rt][ct], 0, 0, 0);
          acc[rt][ct] = __builtin_amdgcn_mfma_f32_16x16x32_bf16(a_lo[rt][ks], bhi, acc[rt][ct], 0, 0, 0);
          acc[rt][ct] = __builtin_amdgcn_mfma_f32_16x16x32_bf16(a_hi[rt][ks], blo, acc[rt][ct], 0, 0, 0);
        }
      }
    }

    // epilogue: logits + online softmax stats + top-2
    float cn[4];
    #pragma unroll
    for (int ct = 0; ct < 4; ++ct) cn[ct] = cnorm[ch * 64 + ct * 16 + lr];
    const int kb = ch * 64;
    #pragma unroll
    for (int rt = 0; rt < 2; ++rt)
      #pragma unroll
      for (int j = 0; j < 4; ++j) {
        const int r8 = rt * 4 + j;
        float lv[4];
        #pragma unroll
        for (int ct = 0; ct < 4; ++ct) lv[ct] = w * (2.f * acc[rt][ct][j] - cn[ct]);
        float lm = fmaxf(fmaxf(lv[0], lv[1]), fmaxf(lv[2], lv[3]));
        float mn = fmaxf(m[r8], lm);
        float sc = __expf(m[r8] - mn);
        s2[r8] = sc * fmaf(m[r8] - mn, s1[r8], s2[r8]);
        s1[r8] *= sc;
        #pragma unroll
        for (int ct = 0; ct < 4; ++ct) {
          float tt = lv[ct] - mn;
          float e = __expf(tt);
          s1[r8] += e;
          s2[r8] = fmaf(tt, e, s2[r8]);
          int kk = kb + ct * 16 + lr;
          if (lv[ct] > b1v[r8]) {
            b2v[r8] = b1v[r8]; b2k[r8] = b1k[r8];
            b1v[r8] = lv[ct];  b1k[r8] = kk;
          } else if (lv[ct] > b2v[r8]) {
            b2v[r8] = lv[ct]; b2k[r8] = kk;
          }
        }
        m[r8] = mn;
      }
  }

  // ---- merge 16 lanes (same row group, disjoint code subsets) ----
  #pragma unroll
  for (int st = 1; st < 16; st <<= 1) {
    #pragma unroll
    for (int j = 0; j < 8; ++j) {
      float om = __shfl_xor(m[j], st);
      float o1 = __shfl_xor(s1[j], st);
      float o2 = __shfl_xor(s2[j], st);
      float ov1 = __shfl_xor(b1v[j], st);
      float ov2 = __shfl_xor(b2v[j], st);
      int ok1 = __shfl_xor(b1k[j], st);
      int ok2 = __shfl_xor(b2k[j], st);
      float mn = fmaxf(m[j], om);
      float sa = __expf(m[j] - mn), sb = __expf(om - mn);
      s2[j] = sa * fmaf(m[j] - mn, s1[j], s2[j]) + sb * fmaf(om - mn, o1, o2);
      s1[j] = sa * s1[j] + sb * o1;
      m[j] = mn;
      bool obeats = (ov1 > b1v[j]) || (ov1 == b1v[j] && ok1 < b1k[j]);
      if (obeats) {
        bool mine2 = (b1v[j] > ov2) || (b1v[j] == ov2 && b1k[j] < ok2);
        float nv2 = mine2 ? b1v[j] : ov2;
        int nk2 = mine2 ? b1k[j] : ok2;
        b1v[j] = ov1; b1k[j] = ok1; b2v[j] = nv2; b2k[j] = nk2;
      } else if ((ov1 > b2v[j]) || (ov1 == b2v[j] && ok1 < b2k[j])) {
        b2v[j] = ov1; b2k[j] = ok1;
      }
    }
  }

  // one lane per 16-lane group writes 8 rows' state
  if (lr == 0) {
    #pragma unroll
    for (int rt = 0; rt < 2; ++rt)
      #pragma unroll
      for (int j = 0; j < 4; ++j) {
        const int r8 = rt * 4 + j;
        int r = wv * 32 + rt * 16 + lg * 4 + j;
        float* st = (float*)(smem + 49152 + r * 24);
        st[0] = m[r8]; st[1] = s1[r8]; st[2] = s2[r8];
        ((int*)st)[3] = b1k[r8]; ((int*)st)[4] = b2k[r8];
      }
  }
  __syncthreads();

  // ---- per-row final: exact fp32 rescore of top-2, entropy, histogram ----
  int* fidx = (int*)(smem + 52224);
  float* redb = (float*)(smem + 52736);
  float rowent = 0.f, d2min = 0.f;
  if (t < 128) {
    const float* st = (const float*)(smem + 49152 + t * 24);
    float S1 = st[1], S2 = st[2];
    int k1 = ((const int*)st)[3], k2 = ((const int*)st)[4];
    rowent = S2 / S1 - __logf(S1);
    const float* zp = z + bb * 65536 + p0 + t;
    const float* c1 = cb + k1 * 64;
    const float* c2 = cb + k2 * 64;
    float zn = 0.f, d1 = 0.f, d2 = 0.f;
    #pragma unroll 4
    for (int d4 = 0; d4 < 16; ++d4) {
      f32x4 ca = *(const f32x4*)(c1 + d4 * 4);
      f32x4 cbv = *(const f32x4*)(c2 + d4 * 4);
      #pragma unroll
      for (int e = 0; e < 4; ++e) {
        float v = zp[(d4 * 4 + e) * 1024];
        zn = fmaf(v, v, zn);
        d1 = fmaf(v, ca[e], d1);
        d2 = fmaf(v, cbv[e], d2);
      }
    }
    const float* cnf = (const float*)(ws + WS_CNORM_B);
    float da = zn + cnf[k1] - 2.f * d1;
    float db = zn + cnf[k2] - 2.f * d2;
    int kwin; float dwin;
    if (da < db || (da == db && k1 < k2)) { kwin = k1; dwin = da; }
    else { kwin = k2; dwin = db; }
    fidx[t] = kwin;
    d2min = dwin;
    atomicAdd((unsigned*)(ws + WS_COUNTS_B) + kwin, 1u);
  }
  #pragma unroll
  for (int o = 32; o > 0; o >>= 1) {
    rowent += __shfl_down(rowent, o);
    d2min += __shfl_down(d2min, o);
  }
  if (t < 128 && l == 0) { redb[wv * 2] = rowent; redb[wv * 2 + 1] = d2min; }
  __syncthreads();
  if (t == 0) {
    float pd = redb[0] + redb[2];
    float pc = redb[1] + redb[3];
    float* wsf = (float*)ws;
    int slot = b & 63;
    atomicAdd(&wsf[slot * 2], pd);
    atomicAdd(&wsf[slot * 2 + 1], pc);
  }
  __syncthreads();

  // ---- gather chosen codes via LDS, write transposed output coalesced ----
  float* zl = (float*)smem;  // 8192 words (z staging area, dead now)
  for (int i = 0; i < 32; ++i) {
    int idx = t + i * 256;
    int r = idx >> 6, d = idx & 63;
    zl[qw(r, d)] = cb[(fidx[r] << 6) + d];
  }
  __syncthreads();
  float* outz = out + bb * 65536 + p0;
  #pragma unroll
  for (int i = 0; i < 8; ++i) {
    int q = t + i * 256;
    int d = q >> 5, rq = q & 31;
    int r = rq << 2;
    f32x4 v;
    v.x = zl[qw(r + 0, d)];
    v.y = zl[qw(r + 1, d)];
    v.z = zl[qw(r + 2, d)];
    v.w = zl[qw(r + 3, d)];
    *(f32x4*)&outz[d * 1024 + r] = v;
  }
}

__global__ __launch_bounds__(1024) void vq_finalize(const float* __restrict__ var_q,
                                                    char* __restrict__ ws,
                                                    float* __restrict__ out) {
  __shared__ float red[48];
  int t = threadIdx.x;
  const unsigned* counts = (const unsigned*)(ws + WS_COUNTS_B);
  const float* wsf = (const float*)ws;
  float avg = (float)counts[t] * (1.0f / 65536.0f);
  float term = avg * __logf(avg + 1e-7f);
  float pd = 0.f, pc = 0.f;
  if (t < 64) { pd = wsf[2 * t]; pc = wsf[2 * t + 1]; }
  #pragma unroll
  for (int o = 32; o > 0; o >>= 1) {
    term += __shfl_down(term, o);
    pd += __shfl_down(pd, o);
    pc += __shfl_down(pc, o);
  }
  int wv = t >> 6, lane = t & 63;
  if (lane == 0) { red[wv * 3] = term; red[wv * 3 + 1] = pd; red[wv * 3 + 2] = pc; }
  __syncthreads();
  if (t == 0) {
    float ts = 0.f, ps = 0.f, cs = 0.f;
    #pragma unroll
    for (int i = 0; i < 16; ++i) {
      ts += red[i * 3]; ps += red[i * 3 + 1]; cs += red[i * 3 + 2];
    }
    float w = 0.5f / fmaxf(var_q[0], 1e-10f);
    out[4194304] = ps / 64.f + w * cs / 64.f;
    out[4194305] = __expf(-ts);
  }
}

extern "C" void kernel_launch(void* const* d_in, const int* in_sizes, int n_in,
                              void* d_out, int out_size, void* d_ws, size_t ws_size,
                              hipStream_t stream) {
  const float* z = (const float*)d_in[0];
  const float* vq = (const float*)d_in[1];
  const float* cb = (const float*)d_in[2];
  float* out = (float*)d_out;
  char* ws = (char*)d_ws;

  hipMemsetAsync(d_ws, 0, WS_ZERO_B, stream);
  vq_prep<<<256, 256, 0, stream>>>(cb, ws);
  vq_main<<<512, 256, 0, stream>>>(z, cb, vq, ws, out);
  vq_finalize<<<1, 1024, 0, stream>>>(vq, ws, out);
}

// Round 3
// 87.566 us; speedup vs baseline: 1.8467x; 1.6378x over previous
//
#include <hip/hip_runtime.h>

// Gaussian VQ forward, split-bf16 MFMA, low-register-pressure version.
// bs=64, dim_z=64, W=H=32 -> N=65536 rows, K=1024 codes, D=64.
//
// ws layout (bytes):
//   [0    ..  511] : 64 (kld_discrete, kld_continuous) partial pairs (float)
//   [512  .. 4607] : cnorm[1024] fp32
//   [4608 .. 8703] : counts[1024] uint
//   [8704 ..     ] : cb_hi bf16[1024][64]  (131072 B)
//   [139776 ..   ] : cb_lo bf16[1024][64]  (131072 B)
#define WS_CNORM_B  512
#define WS_COUNTS_B 4608
#define WS_CBHI_B   8704
#define WS_CBLO_B   139776
#define WS_ZERO_B   8704

typedef __attribute__((ext_vector_type(8))) short short8;
typedef __attribute__((ext_vector_type(4))) float f32x4;

__device__ __forceinline__ unsigned short f2bf(float x) {
  unsigned u = __builtin_bit_cast(unsigned, x);
  u += 0x7fffu + ((u >> 16) & 1u);
  return (unsigned short)(u >> 16);
}
__device__ __forceinline__ float bf2f(unsigned short h) {
  unsigned u = ((unsigned)h) << 16;
  return __builtin_bit_cast(float, u);
}
__device__ __forceinline__ int qw(int r, int d) {
  return (r << 6) | (d ^ (r & 31));
}

// ---- prep: codebook -> bf16 hi/lo splits + ||c||^2 ----
__global__ __launch_bounds__(256) void vq_prep(const float* __restrict__ cb,
                                               char* __restrict__ ws) {
  int tid = blockIdx.x * 256 + threadIdx.x;   // 65536 = 1024*64
  int k = tid >> 6, d = threadIdx.x & 63;
  float v = cb[tid];
  unsigned short hi = f2bf(v);
  unsigned short lo = f2bf(v - bf2f(hi));
  ((unsigned short*)(ws + WS_CBHI_B))[tid] = hi;
  ((unsigned short*)(ws + WS_CBLO_B))[tid] = lo;
  float s = v * v;
  #pragma unroll
  for (int o = 32; o > 0; o >>= 1) s += __shfl_down(s, o);
  if (d == 0) ((float*)(ws + WS_CNORM_B))[k] = s;
}

// ---- main ----
// 512 blocks x 512 threads; block owns 128 rows; wave owns 16 rows x all codes.
// LDS (bytes): bufA [0,16384), bufB [16384,32768)  (chunk dbuf; also z hi/lo
// during prologue; also fp32 out-gather buffer at the end)
//   state [32768, 35328): 128 rows x {m,S1,S2,k1,k2} (20 B)
//   fidx  [35328, 35840) ; redb [35840, 35904)
__global__ __launch_bounds__(512) void vq_main(const float* __restrict__ z,
                                               const float* __restrict__ cb,
                                               const float* __restrict__ var_q,
                                               char* __restrict__ ws,
                                               float* __restrict__ out) {
  __shared__ __align__(16) char smem[35968];

  const int t = threadIdx.x;
  const int b = blockIdx.x;
  const int bb = b >> 3, p0 = (b & 7) << 7;
  const int l = t & 63, wv = t >> 6;
  const int lg = l >> 4, lr = l & 15;
  const float w = 0.5f / fmaxf(var_q[0], 1e-10f);
  const float w2 = 2.f * w;
  const float nw = -w;

  // ---- stage z -> bufA(hi), bufB(lo), swizzled [p][d], one u32 = 2 bf16 ----
  for (int i = 0; i < 8; ++i) {
    int idx = t + i * 512;             // 4096 u32 slots: p(128) x d2(32)
    int d2 = idx >> 7, p = idx & 127;
    float v0 = z[bb * 65536 + (2 * d2) * 1024 + p0 + p];
    float v1 = z[bb * 65536 + (2 * d2 + 1) * 1024 + p0 + p];
    unsigned short h0 = f2bf(v0), h1 = f2bf(v1);
    unsigned short o0 = f2bf(v0 - bf2f(h0)), o1 = f2bf(v1 - bf2f(h1));
    int byte = (p * 128 + d2 * 4) ^ ((p & 7) << 4);
    *(unsigned*)(smem + byte) = ((unsigned)h1 << 16) | h0;
    *(unsigned*)(smem + 16384 + byte) = ((unsigned)o1 << 16) | o0;
  }
  __syncthreads();

  // ---- A fragments for this wave's 16 rows (persistent, 16 VGPR) ----
  short8 a_hi[2], a_lo[2];
  {
    int row = wv * 16 + lr;
    #pragma unroll
    for (int ks = 0; ks < 2; ++ks) {
      int byte = (row * 128 + ks * 64 + lg * 16) ^ ((row & 7) << 4);
      a_hi[ks] = *(const short8*)(smem + byte);
      a_lo[ks] = *(const short8*)(smem + 16384 + byte);
    }
  }
  __syncthreads();  // z reads done; bufs now free for chunk staging

  // ---- prologue: stage chunk 0 ----
  const char* cbh = ws + WS_CBHI_B;
  const char* cbl = ws + WS_CBLO_B;
  const int wdst = (t * 16) ^ (((t >> 3) & 7) << 4);  // swizzled dst in 8KB half
  {
    f32x4 rh = *(const f32x4*)(cbh + t * 16);
    f32x4 rl = *(const f32x4*)(cbl + t * 16);
    *(f32x4*)(smem + wdst) = rh;
    *(f32x4*)(smem + 8192 + wdst) = rl;
  }
  __syncthreads();

  // per-lane state for 4 rows (row = wv*16 + lg*4 + j), codes ct*16+lr (+64/ch)
  float m[4], S1[4], S2[4], b1v[4], b2v[4];
  int k1[4], k2[4], kk[4];
  #pragma unroll
  for (int j = 0; j < 4; ++j) {
    m[j] = -1e30f; S1[j] = 0.f; S2[j] = 0.f;
    b1v[j] = -1e30f; b2v[j] = -1e30f; k1[j] = 0; k2[j] = 0;
  }
  #pragma unroll
  for (int ct = 0; ct < 4; ++ct) kk[ct] = ct * 16 + lr;

  for (int ch = 0; ch < 16; ++ch) {
    char* cur = smem + (ch & 1) * 16384;
    char* nxt = smem + ((ch + 1) & 1) * 16384;
    f32x4 rh, rl;
    const bool pf = ch < 15;
    if (pf) {  // prefetch next chunk into regs; latency hides under compute
      rh = *(const f32x4*)(cbh + (ch + 1) * 8192 + t * 16);
      rl = *(const f32x4*)(cbl + (ch + 1) * 8192 + t * 16);
    }
    const float* cn = (const float*)(ws + WS_CNORM_B) + ch * 64;
    float cn2[4];
    #pragma unroll
    for (int ct = 0; ct < 4; ++ct) cn2[ct] = nw * cn[ct * 16 + lr];

    f32x4 acc[4] = {};
    #pragma unroll
    for (int ct = 0; ct < 4; ++ct) {
      #pragma unroll
      for (int ks = 0; ks < 2; ++ks) {
        int cr = ct * 16 + lr;
        int byte = (cr * 128 + ks * 64 + lg * 16) ^ ((cr & 7) << 4);
        short8 bh = *(const short8*)(cur + byte);
        short8 bo = *(const short8*)(cur + 8192 + byte);
        acc[ct] = __builtin_amdgcn_mfma_f32_16x16x32_bf16(a_hi[ks], bh, acc[ct], 0, 0, 0);
        acc[ct] = __builtin_amdgcn_mfma_f32_16x16x32_bf16(a_lo[ks], bh, acc[ct], 0, 0, 0);
        acc[ct] = __builtin_amdgcn_mfma_f32_16x16x32_bf16(a_hi[ks], bo, acc[ct], 0, 0, 0);
      }
    }

    // epilogue: logits, online softmax (S2 = sum l*e^{l-m}), branchless top-2
    #pragma unroll
    for (int j = 0; j < 4; ++j) {
      float lv[4];
      #pragma unroll
      for (int ct = 0; ct < 4; ++ct) lv[ct] = fmaf(acc[ct][j], w2, cn2[ct]);
      float lm = fmaxf(fmaxf(lv[0], lv[1]), fmaxf(lv[2], lv[3]));
      float mn = fmaxf(m[j], lm);
      float sc = __expf(m[j] - mn);
      S1[j] *= sc; S2[j] *= sc; m[j] = mn;
      #pragma unroll
      for (int ct = 0; ct < 4; ++ct) {
        float e = __expf(lv[ct] - mn);
        S1[j] += e;
        S2[j] = fmaf(lv[ct], e, S2[j]);
        bool g1 = lv[ct] > b1v[j];
        bool g2 = lv[ct] > b2v[j];
        int kc = kk[ct];
        k2[j] = g2 ? kc : k2[j];
        k2[j] = g1 ? k1[j] : k2[j];
        b2v[j] = fmaxf(b2v[j], fminf(b1v[j], lv[ct]));
        k1[j] = g1 ? kc : k1[j];
        b1v[j] = fmaxf(b1v[j], lv[ct]);
      }
    }
    #pragma unroll
    for (int ct = 0; ct < 4; ++ct) kk[ct] += 64;

    if (pf) {
      *(f32x4*)(nxt + wdst) = rh;
      *(f32x4*)(nxt + 8192 + wdst) = rl;
    }
    __syncthreads();
  }

  // ---- merge the 16 code-columns (lanes lr=0..15 within each lg group) ----
  #pragma unroll
  for (int st = 1; st < 16; st <<= 1) {
    #pragma unroll
    for (int j = 0; j < 4; ++j) {
      float om = __shfl_xor(m[j], st);
      float o1 = __shfl_xor(S1[j], st);
      float o2 = __shfl_xor(S2[j], st);
      float ov1 = __shfl_xor(b1v[j], st);
      float ov2 = __shfl_xor(b2v[j], st);
      int ok1 = __shfl_xor(k1[j], st);
      int ok2 = __shfl_xor(k2[j], st);
      float mn = fmaxf(m[j], om);
      float sa = __expf(m[j] - mn), sb = __expf(om - mn);
      S1[j] = sa * S1[j] + sb * o1;
      S2[j] = sa * S2[j] + sb * o2;
      m[j] = mn;
      bool ob = (ov1 > b1v[j]) || (ov1 == b1v[j] && ok1 < k1[j]);
      if (ob) {
        bool m2nd = (b1v[j] > ov2) || (b1v[j] == ov2 && k1[j] < ok2);
        float nv2 = m2nd ? b1v[j] : ov2;
        int nk2 = m2nd ? k1[j] : ok2;
        b1v[j] = ov1; k1[j] = ok1; b2v[j] = nv2; k2[j] = nk2;
      } else if ((ov1 > b2v[j]) || (ov1 == b2v[j] && ok1 < k2[j])) {
        b2v[j] = ov1; k2[j] = ok1;
      }
    }
  }

  float* stw = (float*)(smem + 32768);
  if (lr == 0) {
    #pragma unroll
    for (int j = 0; j < 4; ++j) {
      int r = wv * 16 + lg * 4 + j;
      float* p = stw + r * 5;
      p[0] = m[j]; p[1] = S1[j]; p[2] = S2[j];
      ((int*)p)[3] = k1[j]; ((int*)p)[4] = k2[j];
    }
  }
  __syncthreads();

  // ---- per-row tail: exact fp32 rescore of top-2, entropy, histogram ----
  int* fidx = (int*)(smem + 35328);
  float* redb = (float*)(smem + 35840);
  float rowent = 0.f, d2min = 0.f;
  if (t < 128) {
    const float* p = stw + t * 5;
    float M = p[0], s1 = p[1], s2 = p[2];
    int ka = ((const int*)p)[3], kb = ((const int*)p)[4];
    rowent = (s2 - M * s1) / s1 - __logf(s1);
    const float* zp = z + bb * 65536 + p0 + t;
    const float* c1 = cb + ka * 64;
    const float* c2 = cb + kb * 64;
    float zn = 0.f, d1 = 0.f, d2 = 0.f;
    #pragma unroll 4
    for (int d4 = 0; d4 < 16; ++d4) {
      f32x4 ca = *(const f32x4*)(c1 + d4 * 4);
      f32x4 cc = *(const f32x4*)(c2 + d4 * 4);
      #pragma unroll
      for (int e = 0; e < 4; ++e) {
        float v = zp[(d4 * 4 + e) * 1024];
        zn = fmaf(v, v, zn);
        d1 = fmaf(v, ca[e], d1);
        d2 = fmaf(v, cc[e], d2);
      }
    }
    const float* cnf = (const float*)(ws + WS_CNORM_B);
    float da = zn + cnf[ka] - 2.f * d1;
    float db = zn + cnf[kb] - 2.f * d2;
    int kwin; float dwin;
    if (da < db || (da == db && ka < kb)) { kwin = ka; dwin = da; }
    else { kwin = kb; dwin = db; }
    fidx[t] = kwin;
    d2min = dwin;
    atomicAdd((unsigned*)(ws + WS_COUNTS_B) + kwin, 1u);
  }
  #pragma unroll
  for (int o = 32; o > 0; o >>= 1) {
    rowent += __shfl_down(rowent, o);
    d2min += __shfl_down(d2min, o);
  }
  if (t < 128 && l == 0) { redb[wv * 2] = rowent; redb[wv * 2 + 1] = d2min; }
  __syncthreads();
  if (t == 0) {
    float pd = redb[0] + redb[2];
    float pc = redb[1] + redb[3];
    float* wsf = (float*)ws;
    int slot = b & 63;
    atomicAdd(&wsf[slot * 2], pd);
    atomicAdd(&wsf[slot * 2 + 1], pc);
  }
  __syncthreads();

  // ---- gather chosen codes via LDS (fp32), write transposed coalesced ----
  float* zl = (float*)smem;  // 32KB buf region, dead now
  for (int i = 0; i < 16; ++i) {
    int idx = t + i * 512;
    int r = idx >> 6, d = idx & 63;
    zl[qw(r, d)] = cb[fidx[r] * 64 + d];
  }
  __syncthreads();
  float* outz = out + bb * 65536 + p0;
  #pragma unroll
  for (int i = 0; i < 4; ++i) {
    int q = t + i * 512;
    int d = q >> 5, rq = q & 31, r = rq << 2;
    f32x4 v;
    v.x = zl[qw(r + 0, d)];
    v.y = zl[qw(r + 1, d)];
    v.z = zl[qw(r + 2, d)];
    v.w = zl[qw(r + 3, d)];
    *(f32x4*)&outz[d * 1024 + r] = v;
  }
}

__global__ __launch_bounds__(1024) void vq_finalize(const float* __restrict__ var_q,
                                                    char* __restrict__ ws,
                                                    float* __restrict__ out) {
  __shared__ float red[48];
  int t = threadIdx.x;
  const unsigned* counts = (const unsigned*)(ws + WS_COUNTS_B);
  const float* wsf = (const float*)ws;
  float avg = (float)counts[t] * (1.0f / 65536.0f);
  float term = avg * __logf(avg + 1e-7f);
  float pd = 0.f, pc = 0.f;
  if (t < 64) { pd = wsf[2 * t]; pc = wsf[2 * t + 1]; }
  #pragma unroll
  for (int o = 32; o > 0; o >>= 1) {
    term += __shfl_down(term, o);
    pd += __shfl_down(pd, o);
    pc += __shfl_down(pc, o);
  }
  int wv = t >> 6, lane = t & 63;
  if (lane == 0) { red[wv * 3] = term; red[wv * 3 + 1] = pd; red[wv * 3 + 2] = pc; }
  __syncthreads();
  if (t == 0) {
    float ts = 0.f, ps = 0.f, cs = 0.f;
    #pragma unroll
    for (int i = 0; i < 16; ++i) {
      ts += red[i * 3]; ps += red[i * 3 + 1]; cs += red[i * 3 + 2];
    }
    float w = 0.5f / fmaxf(var_q[0], 1e-10f);
    out[4194304] = ps / 64.f + w * cs / 64.f;
    out[4194305] = __expf(-ts);
  }
}

extern "C" void kernel_launch(void* const* d_in, const int* in_sizes, int n_in,
                              void* d_out, int out_size, void* d_ws, size_t ws_size,
                              hipStream_t stream) {
  const float* z = (const float*)d_in[0];
  const float* vq = (const float*)d_in[1];
  const float* cb = (const float*)d_in[2];
  float* out = (float*)d_out;
  char* ws = (char*)d_ws;

  hipMemsetAsync(d_ws, 0, WS_ZERO_B, stream);
  vq_prep<<<256, 256, 0, stream>>>(cb, ws);
  vq_main<<<512, 512, 0, stream>>>(z, cb, vq, ws, out);
  vq_finalize<<<1, 1024, 0, stream>>>(vq, ws, out);
}